// Round 7
// baseline (81128.979 us; speedup 1.0000x reference)
//
#include <hip/hip_runtime.h>
#include <cstdint>
#include <cstddef>
#include <math.h>

#define B_   32
#define S_   2048
#define IN_  128
#define H_   256
#define Q_   16
#define M_   64
#define D_   4      // layer-1 lag (LDS a-ring depth 8 > D+1)

__device__ __forceinline__ float4 ld4(const float* p) { return *(const float4*)p; }

#define AGLD(p)    __hip_atomic_load((p),  __ATOMIC_RELAXED, __HIP_MEMORY_SCOPE_AGENT)
#define AGST(p, v) __hip_atomic_store((p), (v), __ATOMIC_RELAXED, __HIP_MEMORY_SCOPE_AGENT)

// ---------------------------------------------------------------------------
// Fused 2-layer LSTM recurrence, TWO batch rows per block.
// 128 blocks = 16 groups x 8; 1 block/CU -> co-resident. Block owns 128 gate
// rows (4 gates x 32 cols) of each layer, for BOTH of its rows (weights
// shared). Whh0/Whh1/Wih0 slices in VGPR/AGPR; Wih1 streamed from global
// (L1/L2-resident, off critical path). Cross-block exchange: tagged dword
// pairs (tag<<16 | fp32-half) in a parity-2 ring, agent-scope relaxed
// atomics; both rows publish/poll in the same window (wait paid once per
// two row-steps). All-fp32 math (bf16 flips kNN top-3 -> 0.46 absmax).
// ---------------------------------------------------------------------------
__global__ __launch_bounds__(256, 1) void lstm2(
    const float* __restrict__ x,     // [B,S,128]
    const float* __restrict__ Wih0, const float* __restrict__ bih0,
    const float* __restrict__ bhh0, const float* __restrict__ Whh0,
    const float* __restrict__ Wih1, const float* __restrict__ bih1,
    const float* __restrict__ bhh1, const float* __restrict__ Whh1,
    float* __restrict__ out,         // [B,S,256]  (= d_out, layer-1 hidden)
    unsigned int* __restrict__ ex)   // [32 rows][2q][2p][2plane][256] dwords
{
  const int f = blockIdx.x;
  const int n = (f >> 3) & 7;              // block-in-group
  const int g = (f >> 6) * 8 + (f & 7);    // group (XCD-swizzled), 0..15
  const int rA = 2 * g, rB = 2 * g + 1;    // the two batch rows

  const int tid  = threadIdx.x;
  const int w    = tid >> 6;               // gate 0..3
  const int l    = tid & 63;
  const int cl   = l >> 1;                 // col-in-slice 0..31
  const int half = l & 1;                  // K half

  __shared__ float aringA[8][256], aringB[8][256];
  __shared__ float h_shA[256], h_shB[256];
  __shared__ float x_shA[2][IN_], x_shB[2][IN_];
  __shared__ float g0A_sh[4][32], g1A_sh[4][32];
  __shared__ float g0B_sh[4][32], g1B_sh[4][32];

#pragma unroll
  for (int s2 = 0; s2 < 8; s2++) { aringA[s2][tid] = 0.0f; aringB[s2][tid] = 0.0f; }
  h_shA[tid] = 0.0f; h_shB[tid] = 0.0f;

  const int grow = w * 256 + n * 32 + cl;  // global gate row

  // register-resident weights (shared by both rows)
  float4 wf0[32], wf1[32], wi0[16];
  {
    const float* p0  = Whh0 + (size_t)grow * 256 + half * 128;
    const float* p1  = Whh1 + (size_t)grow * 256 + half * 128;
    const float* pi0 = Wih0 + (size_t)grow * IN_ + half * 64;
#pragma unroll
    for (int i = 0; i < 32; i++) { wf0[i] = ld4(p0 + 4 * i); wf1[i] = ld4(p1 + 4 * i); }
#pragma unroll
    for (int i = 0; i < 16; i++) wi0[i] = ld4(pi0 + 4 * i);
  }
  const float* wi1g = Wih1 + (size_t)grow * 256 + half * 128;  // streamed L2
  const float rb0 = (half == 0) ? (bih0[grow] + bhh0[grow]) : 0.0f;
  const float rb1 = (half == 0) ? (bih1[grow] + bhh1[grow]) : 0.0f;

  const float* xrowA = x + (size_t)rA * S_ * IN_;
  const float* xrowB = x + (size_t)rB * S_ * IN_;
  float* outpA = out + (size_t)rA * S_ * H_;
  float* outpB = out + (size_t)rB * S_ * H_;
  unsigned int* exbA = ex + (size_t)rA * 2048;
  unsigned int* exbB = ex + (size_t)rB * 2048;

  if (tid < IN_) {
    x_shA[0][tid] = xrowA[tid]; x_shA[1][tid] = xrowA[IN_ + tid];
    x_shB[0][tid] = xrowB[tid]; x_shB[1][tid] = xrowB[IN_ + tid];
  }
  float xregA = (tid < IN_) ? xrowA[(size_t)2 * IN_ + tid] : 0.0f;
  float xregB = (tid < IN_) ? xrowB[(size_t)2 * IN_ + tid] : 0.0f;
  float cst = 0.0f;                        // cell state (per wave: A0,A1,B0,B1)
  float xa1A = 0.0f, xa1B = 0.0f;
  __syncthreads();

  // xa0 for t=0
  float xa0A, xa0B;
  {
    const float* xbA = &x_shA[0][half * 64];
    const float* xbB = &x_shB[0][half * 64];
    float4 sA = {0, 0, 0, 0}, sB = {0, 0, 0, 0};
#pragma unroll
    for (int i = 0; i < 16; i++) {
      float4 vA = *(const float4*)(xbA + 4 * i);
      float4 vB = *(const float4*)(xbB + 4 * i);
      sA.x += wi0[i].x * vA.x; sA.y += wi0[i].y * vA.y;
      sA.z += wi0[i].z * vA.z; sA.w += wi0[i].w * vA.w;
      sB.x += wi0[i].x * vB.x; sB.y += wi0[i].y * vB.y;
      sB.z += wi0[i].z * vB.z; sB.w += wi0[i].w * vB.w;
    }
    xa0A = (sA.x + sA.y) + (sA.z + sA.w) + rb0;
    xa0B = (sB.x + sB.y) + (sB.z + sB.w) + rb0;
  }

  bool dead = false;
  for (int t = 0; t < S_ + D_; ++t) {
    const bool doA = (t < S_);             // layer-0 active (both rows)
    const int  u   = t - D_;
    const bool doH = (u >= 0);             // layer-1 active (both rows)

    // ---- 1. critical gate dots (register weights) ----------------------
    float g0A = 0.0f, g1A = 0.0f, g0B = 0.0f, g1B = 0.0f;
    if (doA) {
      const float* apA = &aringA[(t - 1) & 7][half * 128];
      const float* apB = &aringB[(t - 1) & 7][half * 128];
      float4 sA = {0, 0, 0, 0}, sB = {0, 0, 0, 0};
#pragma unroll
      for (int i = 0; i < 32; i++) {
        float4 vA = *(const float4*)(apA + 4 * i);
        float4 vB = *(const float4*)(apB + 4 * i);
        sA.x += wf0[i].x * vA.x; sA.y += wf0[i].y * vA.y;
        sA.z += wf0[i].z * vA.z; sA.w += wf0[i].w * vA.w;
        sB.x += wf0[i].x * vB.x; sB.y += wf0[i].y * vB.y;
        sB.z += wf0[i].z * vB.z; sB.w += wf0[i].w * vB.w;
      }
      g0A = (sA.x + sA.y) + (sA.z + sA.w) + xa0A;
      g0B = (sB.x + sB.y) + (sB.z + sB.w) + xa0B;
      g0A += __shfl_xor(g0A, 1);
      g0B += __shfl_xor(g0B, 1);
    }
    if (doH) {
      const float* hpA = &h_shA[half * 128];
      const float* hpB = &h_shB[half * 128];
      float4 sA = {0, 0, 0, 0}, sB = {0, 0, 0, 0};
#pragma unroll
      for (int i = 0; i < 32; i++) {
        float4 vA = *(const float4*)(hpA + 4 * i);
        float4 vB = *(const float4*)(hpB + 4 * i);
        sA.x += wf1[i].x * vA.x; sA.y += wf1[i].y * vA.y;
        sA.z += wf1[i].z * vA.z; sA.w += wf1[i].w * vA.w;
        sB.x += wf1[i].x * vB.x; sB.y += wf1[i].y * vB.y;
        sB.z += wf1[i].z * vB.z; sB.w += wf1[i].w * vB.w;
      }
      g1A = (sA.x + sA.y) + (sA.z + sA.w) + xa1A;
      g1B = (sB.x + sB.y) + (sB.z + sB.w) + xa1B;
      g1A += __shfl_xor(g1A, 1);
      g1B += __shfl_xor(g1B, 1);
    }
    if (half == 0) {
      if (doA) { g0A_sh[w][cl] = g0A; g0B_sh[w][cl] = g0B; }
      if (doH) { g1A_sh[w][cl] = g1A; g1B_sh[w][cl] = g1B; }
    }
    __syncthreads();

    // ---- 2. cells + tagged publish (one wave per row-layer) ------------
    {
      const int lw = tid >> 6, j = tid & 63;
      if (j < 32) {
        const bool act = (lw == 0 || lw == 2) ? doA : doH;
        if (act) {
          const float (*gs)[32] =
              (lw == 0) ? g0A_sh : (lw == 1) ? g1A_sh : (lw == 2) ? g0B_sh : g1B_sh;
          float gi = gs[0][j], gf = gs[1][j], gg = gs[2][j], go = gs[3][j];
          float ig = 1.0f / (1.0f + expf(-gi));
          float fg = 1.0f / (1.0f + expf(-gf));
          float cg = tanhf(gg);
          float og = 1.0f / (1.0f + expf(-go));
          cst = fg * cst + ig * cg;
          float hv = og * tanhf(cst);
          unsigned bits = __float_as_uint(hv);
          const int step = (lw == 0 || lw == 2) ? t : u;
          unsigned tag = (unsigned)(step + 1) << 16;
          const int p = step & 1, e = n * 32 + j;
          const int q = (lw == 0 || lw == 2) ? 0 : 1;
          unsigned int* exq = ((lw < 2) ? exbA : exbB) + (((q * 2 + p) * 2) << 8);
          AGST(exq + e,       tag | (bits >> 16));
          AGST(exq + 256 + e, tag | (bits & 0xffffu));
          if (lw == 1) outpA[(size_t)u * H_ + n * 32 + j] = hv;
          if (lw == 3) outpB[(size_t)u * H_ + n * 32 + j] = hv;
        }
      }
    }

    // ---- 3. off-critical-path work (overlaps exchange latency) ---------
    // 3a. next xa0 for both rows
    if (t + 1 < S_) {
      const float* xbA = &x_shA[(t + 1) & 1][half * 64];
      const float* xbB = &x_shB[(t + 1) & 1][half * 64];
      float4 sA = {0, 0, 0, 0}, sB = {0, 0, 0, 0};
#pragma unroll
      for (int i = 0; i < 16; i++) {
        float4 vA = *(const float4*)(xbA + 4 * i);
        float4 vB = *(const float4*)(xbB + 4 * i);
        sA.x += wi0[i].x * vA.x; sA.y += wi0[i].y * vA.y;
        sA.z += wi0[i].z * vA.z; sA.w += wi0[i].w * vA.w;
        sB.x += wi0[i].x * vB.x; sB.y += wi0[i].y * vB.y;
        sB.z += wi0[i].z * vB.z; sB.w += wi0[i].w * vB.w;
      }
      xa0A = (sA.x + sA.y) + (sA.z + sA.w) + rb0;
      xa0B = (sB.x + sB.y) + (sB.z + sB.w) + rb0;
    }
    // 3b. xa1 for layer-1 step v = u+1: Wih1 streamed from global (L1/L2),
    //     fused over both rows (weight read once, 2 FMAs) — fp32 exact.
    {
      const int v = t - D_ + 1;
      if (v >= 0 && v < S_) {
        const float* aA = &aringA[v & 7][half * 128];
        const float* aB = &aringB[v & 7][half * 128];
        float4 sA = {0, 0, 0, 0}, sB = {0, 0, 0, 0};
#pragma unroll 8
        for (int i = 0; i < 32; i++) {
          float4 wv = ld4(wi1g + 4 * i);          // VMEM pipe, cache-hot
          float4 a4A = *(const float4*)(aA + 4 * i);
          float4 a4B = *(const float4*)(aB + 4 * i);
          sA.x += wv.x * a4A.x; sA.y += wv.y * a4A.y;
          sA.z += wv.z * a4A.z; sA.w += wv.w * a4A.w;
          sB.x += wv.x * a4B.x; sB.y += wv.y * a4B.y;
          sB.z += wv.z * a4B.z; sB.w += wv.w * a4B.w;
        }
        xa1A = (sA.x + sA.y) + (sA.z + sA.w) + rb1;
        xa1B = (sB.x + sB.y) + (sB.z + sB.w) + rb1;
      }
    }
    // 3c. x prefetch
    float xregA_n = 0.0f, xregB_n = 0.0f;
    if (tid < IN_ && t + 2 < S_) {
      int tn = (t + 3 < S_) ? t + 3 : S_ - 1;
      xregA_n = xrowA[(size_t)tn * IN_ + tid];
      xregB_n = xrowB[(size_t)tn * IN_ + tid];
    }

    // ---- 4. tagged gathers, both rows in one window --------------------
    if (!dead && (doA || doH)) {
      const unsigned eA = (unsigned)(t + 1) & 0xffffu;
      const unsigned eH = (unsigned)(u + 1) & 0xffffu;
      const int pa = t & 1, ph = u & 1;
      unsigned int* A0 = exbA + ((0 * 2 + pa) * 2 << 8) + tid;   // a-plane row A
      unsigned int* A1 = exbA + ((1 * 2 + ph) * 2 << 8) + tid;   // h-plane row A
      unsigned int* B0 = exbB + ((0 * 2 + pa) * 2 << 8) + tid;
      unsigned int* B1 = exbB + ((1 * 2 + ph) * 2 << 8) + tid;
      unsigned a0h = 0, a0l = 0, a1h = 0, a1l = 0;
      unsigned b0h = 0, b0l = 0, b1h = 0, b1l = 0;
      bool nA0 = doA, nA1 = doH, nB0 = doA, nB1 = doH;
      unsigned guard = 0;
      while (true) {
        if (nA0) { a0h = AGLD(A0); a0l = AGLD(A0 + 256);
                   if ((a0h >> 16) == eA && (a0l >> 16) == eA) nA0 = false; }
        if (nA1) { a1h = AGLD(A1); a1l = AGLD(A1 + 256);
                   if ((a1h >> 16) == eH && (a1l >> 16) == eH) nA1 = false; }
        if (nB0) { b0h = AGLD(B0); b0l = AGLD(B0 + 256);
                   if ((b0h >> 16) == eA && (b0l >> 16) == eA) nB0 = false; }
        if (nB1) { b1h = AGLD(B1); b1l = AGLD(B1 + 256);
                   if ((b1h >> 16) == eH && (b1l >> 16) == eH) nB1 = false; }
        if (!(nA0 | nA1 | nB0 | nB1)) break;
        if (++guard >= (1u << 20)) { dead = true; break; }
      }
      if (doA) {
        aringA[t & 7][tid] = __uint_as_float((a0h << 16) | (a0l & 0xffffu));
        aringB[t & 7][tid] = __uint_as_float((b0h << 16) | (b0l & 0xffffu));
      }
      if (doH) {
        h_shA[tid] = __uint_as_float((a1h << 16) | (a1l & 0xffffu));
        h_shB[tid] = __uint_as_float((b1h << 16) | (b1l & 0xffffu));
      }
    }
    if (tid < IN_ && t < S_) { x_shA[t & 1][tid] = xregA; x_shB[t & 1][tid] = xregB; }
    xregA = xregA_n; xregB = xregB_n;
    __syncthreads();
  }
}

// ---------------------------------------------------------------------------
// kNN memory read. One wave per token. enh = qw * enhanced  [MT,256] fp32.
// ---------------------------------------------------------------------------
__global__ __launch_bounds__(256) void knn_enh(
    const float* __restrict__ lstm, const float* __restrict__ Wcq,
    const float* __restrict__ bcq, const float* __restrict__ keys,
    const float* __restrict__ vals, const float* __restrict__ qwp,
    float* __restrict__ enh)
{
  const int tid  = threadIdx.x;
  const int wave = tid >> 6, lane = tid & 63;
  const int t = blockIdx.x * 4 + wave;

  __shared__ float xsh[4][256];
  __shared__ float qsh[4][16];

  const float* xrow = lstm + (size_t)t * H_;
  float4 x4 = ld4(xrow + lane * 4);
  *(float4*)&xsh[wave][lane * 4] = x4;
  __syncthreads();

  const int j = lane & 15, seg = lane >> 4;
  const float* wrow = Wcq + j * H_ + seg * 64;
  const float* xseg = &xsh[wave][seg * 64];
  float p = 0.0f;
#pragma unroll
  for (int c = 0; c < 64; c += 4) {
    float4 w4 = ld4(wrow + c);
    p += w4.x * xseg[c] + w4.y * xseg[c + 1] + w4.z * xseg[c + 2] + w4.w * xseg[c + 3];
  }
  p += __shfl_xor(p, 16);
  p += __shfl_xor(p, 32);
  float q = tanhf(p + bcq[j]);

  float sq = q * q;
  sq += __shfl_xor(sq, 1); sq += __shfl_xor(sq, 2);
  sq += __shfl_xor(sq, 4); sq += __shfl_xor(sq, 8);
  float qn = q / (sqrtf(sq) + 1e-8f);
  if (lane < 16) qsh[wave][lane] = qn;
  __syncthreads();

  const int m = lane;
  const float* krow = keys + m * Q_;
  float kv[16]; float kn2 = 0.0f;
#pragma unroll
  for (int jj = 0; jj < 16; jj++) { kv[jj] = krow[jj]; kn2 += kv[jj] * kv[jj]; }
  float rn = 1.0f / (sqrtf(kn2) + 1e-8f);
  float sim = 0.0f;
#pragma unroll
  for (int jj = 0; jj < 16; jj++) sim += qsh[wave][jj] * kv[jj];
  sim *= rn;

  float rem = sim;
  float tv[3]; int ti[3];
#pragma unroll
  for (int k = 0; k < 3; k++) {
    float v = rem; int idx = m;
#pragma unroll
    for (int d = 1; d < 64; d <<= 1) {
      float ov = __shfl_xor(v, d);
      int   oi = __shfl_xor(idx, d);
      if (ov > v || (ov == v && oi < idx)) { v = ov; idx = oi; }
    }
    tv[k] = v; ti[k] = idx;
    if (m == idx) rem = -INFINITY;
  }
  float tot = tv[0] + tv[1] + tv[2];

  float ex = 0, ey = 0, ez = 0, ew = 0;
#pragma unroll
  for (int k = 0; k < 3; k++) {
    float4 vv = ld4(vals + (size_t)ti[k] * H_ + lane * 4);
    ex += tv[k] * vv.x; ey += tv[k] * vv.y;
    ez += tv[k] * vv.z; ew += tv[k] * vv.w;
  }
  float inv = (tot > 0.0f) ? 1.0f / tot : 0.0f;
  const float qw = qwp[0];

  float4 o;
  o.x = qw * ex * inv; o.y = qw * ey * inv;
  o.z = qw * ez * inv; o.w = qw * ew * inv;
  *(float4*)&enh[(size_t)t * H_ + lane * 4] = o;
}

// ---------------------------------------------------------------------------
// Final projection, IN-PLACE on io (= d_out). Block owns 64 rows x all 256
// cols; reads its own rows, writes after the K-loop -> race-free in-place.
// ---------------------------------------------------------------------------
__global__ __launch_bounds__(256) void gemm_cat(
    float* __restrict__ io, const float* __restrict__ A2,
    const float* __restrict__ Bw, const float* __restrict__ bias,
    const float* __restrict__ cwp)
{
  __shared__ float As[16][68];
  __shared__ float Bs[16][260];
  const int tid  = threadIdx.x;
  const int row0 = blockIdx.x * 64;
  const int tx = tid & 15, ty = tid >> 4;
  const int lr = tid >> 2;
  const int lk = (tid & 3) << 2;
  const float cw = cwp[0];

  float acc[4][16];
#pragma unroll
  for (int i = 0; i < 4; i++)
#pragma unroll
    for (int j = 0; j < 16; j++) acc[i][j] = 0.0f;

  for (int k0 = 0; k0 < 512; k0 += 16) {
    float4 av;
    if (k0 < 256) {
      av = ld4(io + (size_t)(row0 + lr) * 256 + k0 + lk);
      av.x *= cw; av.y *= cw; av.z *= cw; av.w *= cw;
    } else {
      av = ld4(A2 + (size_t)(row0 + lr) * 256 + (k0 - 256) + lk);
    }
    As[lk + 0][lr] = av.x; As[lk + 1][lr] = av.y;
    As[lk + 2][lr] = av.z; As[lk + 3][lr] = av.w;
    const float* bp = Bw + (size_t)tid * 512 + k0;
#pragma unroll
    for (int q = 0; q < 4; q++) {
      float4 b4 = ld4(bp + 4 * q);
      Bs[4 * q + 0][tid] = b4.x; Bs[4 * q + 1][tid] = b4.y;
      Bs[4 * q + 2][tid] = b4.z; Bs[4 * q + 3][tid] = b4.w;
    }
    __syncthreads();
#pragma unroll
    for (int k = 0; k < 16; k++) {
      float4 a4 = *(const float4*)&As[k][ty << 2];
      float aa[4] = {a4.x, a4.y, a4.z, a4.w};
#pragma unroll
      for (int cc = 0; cc < 4; cc++) {
        float4 b4 = *(const float4*)&Bs[k][cc * 64 + (tx << 2)];
        float bb[4] = {b4.x, b4.y, b4.z, b4.w};
#pragma unroll
        for (int i = 0; i < 4; i++)
#pragma unroll
          for (int jj = 0; jj < 4; jj++) acc[i][cc * 4 + jj] += aa[i] * bb[jj];
      }
    }
    __syncthreads();
  }

#pragma unroll
  for (int i = 0; i < 4; i++) {
#pragma unroll
    for (int cc = 0; cc < 4; cc++) {
      int c0 = cc * 64 + (tx << 2);
      float4 o;
      o.x = acc[i][cc * 4 + 0] + bias[c0 + 0];
      o.y = acc[i][cc * 4 + 1] + bias[c0 + 1];
      o.z = acc[i][cc * 4 + 2] + bias[c0 + 2];
      o.w = acc[i][cc * 4 + 3] + bias[c0 + 3];
      *(float4*)&io[(size_t)(row0 + (ty << 2) + i) * 256 + c0] = o;
    }
  }
}

// ---------------------------------------------------------------------------
extern "C" void kernel_launch(void* const* d_in, const int* in_sizes, int n_in,
                              void* d_out, int out_size, void* d_ws, size_t ws_size,
                              hipStream_t stream)
{
  const float* x    = (const float*)d_in[0];
  const float* Wih0 = (const float*)d_in[1];
  const float* Whh0 = (const float*)d_in[2];
  const float* bih0 = (const float*)d_in[3];
  const float* bhh0 = (const float*)d_in[4];
  const float* Wih1 = (const float*)d_in[5];
  const float* Whh1 = (const float*)d_in[6];
  const float* bih1 = (const float*)d_in[7];
  const float* bhh1 = (const float*)d_in[8];
  const float* Wcq  = (const float*)d_in[9];
  const float* bcq  = (const float*)d_in[10];
  const float* keys = (const float*)d_in[11];
  const float* vals = (const float*)d_in[12];
  const float* Wout = (const float*)d_in[13];
  const float* bout = (const float*)d_in[14];
  const float* cw   = (const float*)d_in[15];
  const float* qw   = (const float*)d_in[16];
  float* out = (float*)d_out;

  // ws: [exchange 256 KB (dead after lstm2)] overlapped with enh [MT,256] f32.
  const size_t HE = (size_t)B_ * S_ * H_;
  if (ws_size < HE * sizeof(float)) return;   // 67.1 MB (proven available)
  unsigned int* ex = (unsigned int*)d_ws;
  float* enh = (float*)d_ws;

  const int MT = B_ * S_;
  dim3 blk(256);

  hipMemsetAsync(ex, 0, (size_t)32 * 2048 * sizeof(unsigned int), stream);
  lstm2<<<dim3(128), blk, 0, stream>>>(x, Wih0, bih0, bhh0, Whh0,
                                       Wih1, bih1, bhh1, Whh1, out, ex);

  knn_enh<<<dim3(MT / 4), blk, 0, stream>>>(out, Wcq, bcq, keys, vals, qw, enh);

  gemm_cat<<<dim3(MT / 64), blk, 0, stream>>>(out, enh, Wout, bout, cw);
}